// Round 4
// baseline (423.593 us; speedup 1.0000x reference)
//
#include <hip/hip_runtime.h>
#include <stdint.h>

typedef __bf16 bf16_t;
typedef bf16_t bf16x8 __attribute__((ext_vector_type(8)));
typedef bf16_t bf16x4 __attribute__((ext_vector_type(4)));
typedef bf16_t bf16x2 __attribute__((ext_vector_type(2)));
typedef float  f32x4  __attribute__((ext_vector_type(4)));

#define IN_C 512
#define HID  256
#define OUTC 128

// ---------------- edge format detection ----------------
__global__ void k_detect(const void* __restrict__ ei, int* __restrict__ flag, int n_nodes) {
  if (blockIdx.x == 0 && threadIdx.x == 0) {
    const long long* p = (const long long*)ei;
    int ok = 1;
    for (int i = 0; i < 64; ++i) {
      long long v = p[i];
      if (v < 0 || v >= n_nodes) ok = 0;
    }
    *flag = ok;  // 1 => int64 layout, 0 => int32 layout
  }
}

__global__ void k_hist(const void* __restrict__ ei, const int* __restrict__ flag,
                       int* __restrict__ cnt, int E) {
  int e = blockIdx.x * blockDim.x + threadIdx.x;
  if (e >= E) return;
  int d;
  if (*flag) d = (int)((const long long*)ei)[(size_t)E + e];
  else       d = ((const int*)ei)[E + e];
  atomicAdd(&cnt[d], 1);
}

// ---------------- CSR build: scan (dinv fused) + fill ----------------
__global__ void k_scan1(const int* __restrict__ cnt, int* __restrict__ ex,
                        int* __restrict__ part, float* __restrict__ dinv, int n) {
  __shared__ int sh[256];
  int i = blockIdx.x * 256 + threadIdx.x;
  int v = (i < n) ? cnt[i] : 0;
  if (i < n) dinv[i] = rsqrtf((float)v + 1.0f);  // +1 self-loop
  sh[threadIdx.x] = v;
  __syncthreads();
  int val = v;
  for (int off = 1; off < 256; off <<= 1) {
    int t = (threadIdx.x >= off) ? sh[threadIdx.x - off] : 0;
    __syncthreads();
    val += t;
    sh[threadIdx.x] = val;
    __syncthreads();
  }
  if (i < n) ex[i] = val - v;
  if (threadIdx.x == 255) part[blockIdx.x] = val;
}

__global__ void k_scan2(int* __restrict__ part, int nb) {
  __shared__ int sh[256];
  int v = (threadIdx.x < nb) ? part[threadIdx.x] : 0;
  sh[threadIdx.x] = v;
  __syncthreads();
  int val = v;
  for (int off = 1; off < 256; off <<= 1) {
    int t = (threadIdx.x >= off) ? sh[threadIdx.x - off] : 0;
    __syncthreads();
    val += t;
    sh[threadIdx.x] = val;
    __syncthreads();
  }
  if (threadIdx.x < nb) part[threadIdx.x] = val - v;
}

__global__ void k_scan3(int* __restrict__ rs, const int* __restrict__ part,
                        int* __restrict__ cur, int n, int Etot) {
  int i = blockIdx.x * 256 + threadIdx.x;
  if (i < n) {
    int r = rs[i] + part[blockIdx.x];
    rs[i] = r;
    cur[i] = r;
  }
  if (i == 0) rs[n] = Etot;
}

// CSR fill; also emits wsrc[e] = dinv[src] to break the gather latency chain
__global__ void k_fill(const void* __restrict__ ei, const int* __restrict__ flag,
                       int* __restrict__ cur, int* __restrict__ csr,
                       float* __restrict__ wsrc, const float* __restrict__ dinv, int E) {
  int e = blockIdx.x * blockDim.x + threadIdx.x;
  if (e >= E) return;
  int s, d;
  if (*flag) {
    const long long* p = (const long long*)ei;
    s = (int)p[e];
    d = (int)p[(size_t)E + e];
  } else {
    const int* p = (const int*)ei;
    s = p[e];
    d = p[E + e];
  }
  int pos = atomicAdd(&cur[d], 1);
  csr[pos] = s;
  wsrc[pos] = dinv[s];
}

// ---------------- weight prep ----------------
// W1 [512,256] -> W1blk [kb][col][64] bf16 (kb = k/64), for coalesced GEMM1 staging.
// W2 [256,128] -> W2t [128,256] bf16 row-major.
__global__ void k_transw(const float* __restrict__ W1, const float* __restrict__ W2,
                         bf16_t* __restrict__ W1blk, bf16_t* __restrict__ W2t) {
  int t = blockIdx.x * blockDim.x + threadIdx.x;
  if (t < IN_C * HID) {
    int k = t >> 8, col = t & 255;
    W1blk[(size_t)(k >> 6) * (HID * 64) + col * 64 + (k & 63)] = (bf16_t)W1[t];
  } else {
    int u = t - IN_C * HID;
    if (u < HID * OUTC) {
      int k = u >> 7, col = u & 127;
      W2t[(size_t)col * HID + k] = (bf16_t)W2[u];
    }
  }
}

// ---------------- GEMM1: H1b[mpad,256] = bf16( x[fp32][n,512] @ W1 ) ----------
// BM=64, BN=256(full), BK=64. A direct-to-register (no LDS), B staged in LDS.
// 4 waves 2x2: wave tile 32x128. 32 MFMA per wave per barrier-pair.
__global__ __launch_bounds__(256, 2) void k_gemm1(const float* __restrict__ x,
                                                  const bf16_t* __restrict__ Bblk,
                                                  bf16_t* __restrict__ C, int n) {
  __shared__ bf16_t Bs[256 * 72];  // 36.9 KB; stride 72 bf16 = benign 2-way banking
  const int bm = blockIdx.x;
  const int tid = threadIdx.x;
  const int wave = tid >> 6, lane = tid & 63;
  const int wm = (wave >> 1) * 32, wn = (wave & 1) * 128;
  const int quad = lane >> 4, l16 = lane & 15;
  const int row0 = bm * 64 + wm + l16;

  f32x4 acc[2][8];
  for (int i = 0; i < 2; ++i)
    for (int j = 0; j < 8; ++j)
      for (int r = 0; r < 4; ++r) acc[i][j][r] = 0.0f;

  for (int kb = 0; kb < 8; ++kb) {
    const int kk = kb * 64;
    // A fragments straight from global (issued before barriers -> overlap drain)
    bf16x8 afr[2][2];
#pragma unroll
    for (int i = 0; i < 2; ++i) {
      int r = row0 + i * 16;
#pragma unroll
      for (int k2 = 0; k2 < 2; ++k2) {
        if (r < n) {
          const float4* p = (const float4*)(x + (size_t)r * IN_C + kk + k2 * 32 + quad * 8);
          float4 a = p[0], b = p[1];
          afr[i][k2][0] = (bf16_t)a.x; afr[i][k2][1] = (bf16_t)a.y;
          afr[i][k2][2] = (bf16_t)a.z; afr[i][k2][3] = (bf16_t)a.w;
          afr[i][k2][4] = (bf16_t)b.x; afr[i][k2][5] = (bf16_t)b.y;
          afr[i][k2][6] = (bf16_t)b.z; afr[i][k2][7] = (bf16_t)b.w;
        } else {
          for (int u = 0; u < 8; ++u) afr[i][k2][u] = (bf16_t)0.0f;
        }
      }
    }
    __syncthreads();  // previous iteration's Bs reads complete
    // stage B tile [256 cols][64 k] — fully coalesced 128 B per thread
    const bf16_t* gb = Bblk + (size_t)kb * (HID * 64) + (size_t)tid * 64;
#pragma unroll
    for (int u = 0; u < 8; ++u) {
      bf16x8 v = *(const bf16x8*)(gb + u * 8);
      *(bf16x8*)(&Bs[tid * 72 + u * 8]) = v;
    }
    __syncthreads();
#pragma unroll
    for (int k2 = 0; k2 < 2; ++k2) {
      bf16x8 bfr[8];
#pragma unroll
      for (int j = 0; j < 8; ++j)
        bfr[j] = *(const bf16x8*)(&Bs[(wn + j * 16 + l16) * 72 + k2 * 32 + quad * 8]);
#pragma unroll
      for (int i = 0; i < 2; ++i)
#pragma unroll
        for (int j = 0; j < 8; ++j)
          acc[i][j] = __builtin_amdgcn_mfma_f32_16x16x32_bf16(afr[i][k2], bfr[j], acc[i][j], 0, 0, 0);
    }
  }

#pragma unroll
  for (int i = 0; i < 2; ++i) {
#pragma unroll
    for (int j = 0; j < 8; ++j) {
      int col = wn + j * 16 + l16;
      int rw0 = bm * 64 + wm + i * 16 + quad * 4;
#pragma unroll
      for (int r = 0; r < 4; ++r)
        C[(size_t)(rw0 + r) * HID + col] = (bf16_t)acc[i][j][r];
    }
  }
}

// ---------------- GEMM2: H2b[mpad,128] = bf16( R1b[mpad,256] @ W2 ) ----------
// B (64 KB) resident in LDS, loaded once; A direct-to-register; no K-loop barriers.
__global__ __launch_bounds__(256, 2) void k_gemm2(const bf16_t* __restrict__ A,
                                                  const bf16_t* __restrict__ W2t,
                                                  bf16_t* __restrict__ C) {
  __shared__ bf16_t Bs[128 * 264];  // 67.6 KB; stride 264 bf16 = benign 2-way
  const int bm = blockIdx.x;
  const int tid = threadIdx.x;
  const int wave = tid >> 6, lane = tid & 63;
  const int wm = (wave >> 1) * 32, wn = (wave & 1) * 64;
  const int quad = lane >> 4, l16 = lane & 15;

  // persistent B load: 4096 16B chunks, coalesced
#pragma unroll
  for (int i = 0; i < 16; ++i) {
    int g = i * 256 + tid;
    int row = g >> 5, cc = g & 31;
    bf16x8 v = *(const bf16x8*)(W2t + (size_t)row * HID + cc * 8);
    *(bf16x8*)(&Bs[row * 264 + cc * 8]) = v;
  }
  __syncthreads();

  f32x4 acc[2][4];
  for (int i = 0; i < 2; ++i)
    for (int j = 0; j < 4; ++j)
      for (int r = 0; r < 4; ++r) acc[i][j][r] = 0.0f;

#pragma unroll
  for (int ks = 0; ks < 8; ++ks) {
    const int kk = ks * 32;
    bf16x8 af[2];
#pragma unroll
    for (int i = 0; i < 2; ++i) {
      int r = bm * 64 + wm + i * 16 + l16;
      af[i] = *(const bf16x8*)(A + (size_t)r * HID + kk + quad * 8);
    }
    bf16x8 bfr[4];
#pragma unroll
    for (int j = 0; j < 4; ++j)
      bfr[j] = *(const bf16x8*)(&Bs[(wn + j * 16 + l16) * 264 + kk + quad * 8]);
#pragma unroll
    for (int i = 0; i < 2; ++i)
#pragma unroll
      for (int j = 0; j < 4; ++j)
        acc[i][j] = __builtin_amdgcn_mfma_f32_16x16x32_bf16(af[i], bfr[j], acc[i][j], 0, 0, 0);
  }

#pragma unroll
  for (int i = 0; i < 2; ++i) {
#pragma unroll
    for (int j = 0; j < 4; ++j) {
      int col = wn + j * 16 + l16;
      int rw0 = bm * 64 + wm + i * 16 + quad * 4;
#pragma unroll
      for (int r = 0; r < 4; ++r)
        C[(size_t)(rw0 + r) * OUTC + col] = (bf16_t)acc[i][j][r];
    }
  }
}

// ---------------- layer-1 aggregation (bf16 gather, 8 in flight) ----------
__global__ void k_agg_l1(const bf16_t* __restrict__ H, const int* __restrict__ rs,
                         const int* __restrict__ csr, const float* __restrict__ wsrc,
                         const float* __restrict__ dinv, const float* __restrict__ b1,
                         bf16_t* __restrict__ R, int n, int mpad) {
  int d = blockIdx.x * 4 + (threadIdx.x >> 6);
  if (d >= mpad) return;
  int lane = threadIdx.x & 63;
  if (d >= n) {
    bf16x4 z;
    z[0] = (bf16_t)0.0f; z[1] = (bf16_t)0.0f; z[2] = (bf16_t)0.0f; z[3] = (bf16_t)0.0f;
    *(bf16x4*)(R + (size_t)d * HID + lane * 4) = z;
    return;
  }
  int e0 = rs[d], e1 = rs[d + 1];
  float acc[4][4];
  for (int k = 0; k < 4; ++k)
    for (int c = 0; c < 4; ++c) acc[k][c] = 0.f;
  int e = e0;
  for (; e + 8 <= e1; e += 8) {
    int   s[8];
    float w[8];
    bf16x4 h[8];
#pragma unroll
    for (int u = 0; u < 8; ++u) { s[u] = csr[e + u]; w[u] = wsrc[e + u]; }
#pragma unroll
    for (int u = 0; u < 8; ++u)
      h[u] = *(const bf16x4*)(H + (size_t)s[u] * HID + lane * 4);
#pragma unroll
    for (int u = 0; u < 8; ++u)
#pragma unroll
      for (int c = 0; c < 4; ++c) acc[u & 3][c] += w[u] * (float)h[u][c];
  }
  for (; e < e1; ++e) {
    int sx = csr[e];
    float wx = wsrc[e];
    bf16x4 hx = *(const bf16x4*)(H + (size_t)sx * HID + lane * 4);
#pragma unroll
    for (int c = 0; c < 4; ++c) acc[0][c] += wx * (float)hx[c];
  }
  float dd = dinv[d];
  float dv2 = dd * dd;
  bf16x4 hs = *(const bf16x4*)(H + (size_t)d * HID + lane * 4);
  float4 bb = ((const float4*)b1)[lane];
  float a0 = (acc[0][0] + acc[1][0]) + (acc[2][0] + acc[3][0]);
  float a1 = (acc[0][1] + acc[1][1]) + (acc[2][1] + acc[3][1]);
  float a2 = (acc[0][2] + acc[1][2]) + (acc[2][2] + acc[3][2]);
  float a3 = (acc[0][3] + acc[1][3]) + (acc[2][3] + acc[3][3]);
  float v0 = fmaxf(a0 * dd + dv2 * (float)hs[0] + bb.x, 0.f);
  float v1 = fmaxf(a1 * dd + dv2 * (float)hs[1] + bb.y, 0.f);
  float v2 = fmaxf(a2 * dd + dv2 * (float)hs[2] + bb.z, 0.f);
  float v3 = fmaxf(a3 * dd + dv2 * (float)hs[3] + bb.w, 0.f);
  bf16x4 o;
  o[0] = (bf16_t)v0; o[1] = (bf16_t)v1; o[2] = (bf16_t)v2; o[3] = (bf16_t)v3;
  *(bf16x4*)(R + (size_t)d * HID + lane * 4) = o;
}

// ---------------- layer-2 aggregation (bf16 gather, 8 in flight) ----------
__global__ void k_agg_l2(const bf16_t* __restrict__ H, const int* __restrict__ rs,
                         const int* __restrict__ csr, const float* __restrict__ wsrc,
                         const float* __restrict__ dinv, const float* __restrict__ b2,
                         float* __restrict__ out, int n) {
  int d = blockIdx.x * 4 + (threadIdx.x >> 6);
  if (d >= n) return;
  int lane = threadIdx.x & 63;
  int e0 = rs[d], e1 = rs[d + 1];
  float acc[4][2];
  for (int k = 0; k < 4; ++k) { acc[k][0] = 0.f; acc[k][1] = 0.f; }
  int e = e0;
  for (; e + 8 <= e1; e += 8) {
    int   s[8];
    float w[8];
    bf16x2 h[8];
#pragma unroll
    for (int u = 0; u < 8; ++u) { s[u] = csr[e + u]; w[u] = wsrc[e + u]; }
#pragma unroll
    for (int u = 0; u < 8; ++u)
      h[u] = *(const bf16x2*)(H + (size_t)s[u] * OUTC + lane * 2);
#pragma unroll
    for (int u = 0; u < 8; ++u) {
      acc[u & 3][0] += w[u] * (float)h[u][0];
      acc[u & 3][1] += w[u] * (float)h[u][1];
    }
  }
  for (; e < e1; ++e) {
    int sx = csr[e];
    float wx = wsrc[e];
    bf16x2 hx = *(const bf16x2*)(H + (size_t)sx * OUTC + lane * 2);
    acc[0][0] += wx * (float)hx[0];
    acc[0][1] += wx * (float)hx[1];
  }
  float a0 = (acc[0][0] + acc[1][0]) + (acc[2][0] + acc[3][0]);
  float a1 = (acc[0][1] + acc[1][1]) + (acc[2][1] + acc[3][1]);
  float dd = dinv[d];
  float dv2 = dd * dd;
  bf16x2 hs = *(const bf16x2*)(H + (size_t)d * OUTC + lane * 2);
  float2 bb = ((const float2*)b2)[lane];
  float2 o;
  o.x = a0 * dd + dv2 * (float)hs[0] + bb.x;
  o.y = a1 * dd + dv2 * (float)hs[1] + bb.y;
  ((float2*)(out + (size_t)d * OUTC))[lane] = o;
}

// ---------------- launch ----------------
extern "C" void kernel_launch(void* const* d_in, const int* in_sizes, int n_in,
                              void* d_out, int out_size, void* d_ws, size_t ws_size,
                              hipStream_t stream) {
  const float* x  = (const float*)d_in[0];
  const void*  ei = d_in[1];
  const float* W1 = (const float*)d_in[2];
  const float* b1 = (const float*)d_in[3];
  const float* W2 = (const float*)d_in[4];
  const float* b2 = (const float*)d_in[5];

  const int n = in_sizes[0] / IN_C;   // 50000
  const int E = in_sizes[1] / 2;      // 800000
  const int mpad = (n + 63) & ~63;    // 50048

  char* w = (char*)d_ws;
  size_t off = 0;
  auto alloc = [&](size_t bytes) -> void* {
    void* p = w + off;
    off = (off + bytes + 255) & ~(size_t)255;
    return p;
  };

  int*    flag = (int*)alloc(4);
  int*    cnt  = (int*)alloc((size_t)n * 4);
  float*  dinv = (float*)alloc((size_t)n * 4);
  int*    rs   = (int*)alloc((size_t)(n + 1) * 4);
  int*    cur  = (int*)alloc((size_t)n * 4);
  int*    part = (int*)alloc(1024);
  int*    csr  = (int*)alloc((size_t)E * 4);
  float*  wsrc = (float*)alloc((size_t)E * 4);
  bf16_t* W1blk= (bf16_t*)alloc((size_t)HID * IN_C * 2);
  bf16_t* W2t  = (bf16_t*)alloc((size_t)OUTC * HID * 2);
  bf16_t* H1b  = (bf16_t*)alloc((size_t)mpad * HID * 2);
  bf16_t* R1b  = (bf16_t*)alloc((size_t)mpad * HID * 2);
  bf16_t* H2b  = (bf16_t*)alloc((size_t)mpad * OUTC * 2);
  (void)ws_size; (void)n_in; (void)out_size;

  const int nb = (n + 255) / 256;

  hipMemsetAsync(cnt, 0, (size_t)n * 4, stream);
  k_detect<<<1, 64, 0, stream>>>(ei, flag, n);
  k_hist<<<(E + 255) / 256, 256, 0, stream>>>(ei, flag, cnt, E);
  k_scan1<<<nb, 256, 0, stream>>>(cnt, rs, part, dinv, n);
  k_scan2<<<1, 256, 0, stream>>>(part, nb);
  k_scan3<<<nb, 256, 0, stream>>>(rs, part, cur, n, E);
  k_fill<<<(E + 255) / 256, 256, 0, stream>>>(ei, flag, cur, csr, wsrc, dinv, E);
  k_transw<<<(IN_C * HID + HID * OUTC + 255) / 256, 256, 0, stream>>>(W1, W2, W1blk, W2t);

  k_gemm1<<<mpad / 64, 256, 0, stream>>>(x, W1blk, H1b, n);
  k_agg_l1<<<(mpad + 3) / 4, 256, 0, stream>>>(H1b, rs, csr, wsrc, dinv, b1, R1b, n, mpad);
  k_gemm2<<<mpad / 64, 256, 0, stream>>>(R1b, W2t, H2b);
  k_agg_l2<<<(n + 3) / 4, 256, 0, stream>>>(H2b, rs, csr, wsrc, dinv, b2, (float*)d_out, n);
}